// Round 5
// baseline (5561.975 us; speedup 1.0000x reference)
//
#include <hip/hip_runtime.h>

// ---------------- model constants ----------------
#define DM    1024      // d_model
#define DI    2048      // d_inner
#define DS    16        // d_state
#define NL    4         // n_layer
#define BB    2
#define LL    1024
#define MTOT  (BB*LL)   // 2048 token rows
#define NVOC  32000

typedef __attribute__((ext_vector_type(8))) short short8;
typedef __attribute__((ext_vector_type(4))) float f32x4;

__device__ __forceinline__ unsigned short f2bf(float f) {
    unsigned u = __float_as_uint(f);
    unsigned r = 0x7FFFu + ((u >> 16) & 1u);   // round-to-nearest-even
    return (unsigned short)((u + r) >> 16);
}
__device__ __forceinline__ float bf2f(unsigned short s) {
    return __uint_as_float(((unsigned)s) << 16);
}
// f32 -> (hi, lo) bf16 pair: hi = RNE(x), lo = RNE(x - hi). ~16 mantissa bits total.
__device__ __forceinline__ void split4(const float4 v, ushort4& hi, ushort4& lo) {
    hi.x = f2bf(v.x); lo.x = f2bf(v.x - bf2f(hi.x));
    hi.y = f2bf(v.y); lo.y = f2bf(v.y - bf2f(hi.y));
    hi.z = f2bf(v.z); lo.z = f2bf(v.z - bf2f(hi.z));
    hi.w = f2bf(v.w); lo.w = f2bf(v.w - bf2f(hi.w));
}

// ---------------- embedding gather (float4 per thread) ----------------
__global__ void embed_kernel(const float* __restrict__ emb, const int* __restrict__ ids,
                             float* __restrict__ x) {
    int i = blockIdx.x * 256 + threadIdx.x;    // over MTOT*256 float4s
    int m = i >> 8, c = i & 255;
    int row = ids[m];
    reinterpret_cast<float4*>(x)[(size_t)m * 256 + c] =
        reinterpret_cast<const float4*>(emb)[(size_t)row * 256 + c];
}

// ---------------- rmsnorm: one block per row of 1024, writes f32 ----------------
__global__ __launch_bounds__(256) void rmsnorm_kernel(const float* __restrict__ x,
                                                      const float* __restrict__ w,
                                                      float* __restrict__ xn) {
    int m = blockIdx.x;
    int t = threadIdx.x;
    float4 v = reinterpret_cast<const float4*>(x + (size_t)m * DM)[t];
    float ss = v.x * v.x + v.y * v.y + v.z * v.z + v.w * v.w;
    #pragma unroll
    for (int s = 32; s; s >>= 1) ss += __shfl_down(ss, s, 64);
    __shared__ float r4[4];
    if ((t & 63) == 0) r4[t >> 6] = ss;
    __syncthreads();
    float tot = r4[0] + r4[1] + r4[2] + r4[3];
    float scale = rsqrtf(tot / (float)DM + 1e-5f);
    float4 wv = reinterpret_cast<const float4*>(w)[t];
    float4 o;
    o.x = v.x * scale * wv.x;
    o.y = v.y * scale * wv.y;
    o.z = v.z * scale * wv.z;
    o.w = v.w * scale * wv.w;
    reinterpret_cast<float4*>(xn)[(size_t)m * (DM / 4) + t] = o;
}

// ---------------- split-precision bf16x3 MFMA GEMM ----------------
// C(MxN) = A(MxK) @ W(NxK)^T, A/W are f32 in global, split to (hi,lo) bf16 in LDS.
// acc += Ah*Wh + Ah*Wl + Al*Wh  (lo*lo term ~2^-18 dropped)
// EPI 0: +bias, write f32
// EPI 1: +bias, silu, write f32
// EPI 2: +bias, accumulate into f32 (x += out-proj)
// EPI 3: plain write f32 (logits, bias unused)
template<int EPI>
__global__ __launch_bounds__(256)
void gemm_split3(const float* __restrict__ A, const float* __restrict__ W,
                 const float* __restrict__ bias, float* __restrict__ outf,
                 int M, int N, int K) {
    __shared__ unsigned short Ah[128][40];   // +8 pad: row stride 80B
    __shared__ unsigned short Al[128][40];
    __shared__ unsigned short Wh[128][40];
    __shared__ unsigned short Wl[128][40];
    const int t = threadIdx.x;
    const int lane = t & 63;
    const int wv = t >> 6;
    const int wr = wv >> 1, wc = wv & 1;       // 2x2 wave grid, 64x64 per wave
    const int r15 = lane & 15, kh = lane >> 4; // fragment row / k-half
    const int m0 = blockIdx.y * 128, n0 = blockIdx.x * 128;

    f32x4 acc[4][4];
    #pragma unroll
    for (int i = 0; i < 4; i++)
        #pragma unroll
        for (int j = 0; j < 4; j++)
            acc[i][j] = (f32x4){0.f, 0.f, 0.f, 0.f};

    for (int k0 = 0; k0 < K; k0 += 32) {
        // stage 128x32 f32 tiles of A and W: 1024 float4-chunks each, 4/thread
        float4 a4[4], w4[4];
        #pragma unroll
        for (int j = 0; j < 4; j++) {
            int ch = t + 256 * j;            // 0..1023
            int row = ch >> 3, c4 = ch & 7;
            a4[j] = *reinterpret_cast<const float4*>(&A[(size_t)(m0 + row) * K + k0 + c4 * 4]);
            w4[j] = *reinterpret_cast<const float4*>(&W[(size_t)(n0 + row) * K + k0 + c4 * 4]);
        }
        __syncthreads();   // previous iteration's readers done
        #pragma unroll
        for (int j = 0; j < 4; j++) {
            int ch = t + 256 * j;
            int row = ch >> 3, c0 = (ch & 7) * 4;
            ushort4 h4, l4;
            split4(a4[j], h4, l4);
            *reinterpret_cast<ushort4*>(&Ah[row][c0]) = h4;
            *reinterpret_cast<ushort4*>(&Al[row][c0]) = l4;
            split4(w4[j], h4, l4);
            *reinterpret_cast<ushort4*>(&Wh[row][c0]) = h4;
            *reinterpret_cast<ushort4*>(&Wl[row][c0]) = l4;
        }
        __syncthreads();
        short8 afh[4], afl[4], wfh[4], wfl[4];
        #pragma unroll
        for (int mf = 0; mf < 4; mf++) {
            afh[mf] = *reinterpret_cast<const short8*>(&Ah[wr * 64 + mf * 16 + r15][kh * 8]);
            afl[mf] = *reinterpret_cast<const short8*>(&Al[wr * 64 + mf * 16 + r15][kh * 8]);
        }
        #pragma unroll
        for (int nf = 0; nf < 4; nf++) {
            wfh[nf] = *reinterpret_cast<const short8*>(&Wh[wc * 64 + nf * 16 + r15][kh * 8]);
            wfl[nf] = *reinterpret_cast<const short8*>(&Wl[wc * 64 + nf * 16 + r15][kh * 8]);
        }
        #pragma unroll
        for (int mf = 0; mf < 4; mf++)
            #pragma unroll
            for (int nf = 0; nf < 4; nf++) {
                acc[mf][nf] = __builtin_amdgcn_mfma_f32_16x16x32_bf16(afh[mf], wfh[nf], acc[mf][nf], 0, 0, 0);
                acc[mf][nf] = __builtin_amdgcn_mfma_f32_16x16x32_bf16(afh[mf], wfl[nf], acc[mf][nf], 0, 0, 0);
                acc[mf][nf] = __builtin_amdgcn_mfma_f32_16x16x32_bf16(afl[mf], wfh[nf], acc[mf][nf], 0, 0, 0);
            }
    }

    #pragma unroll
    for (int mf = 0; mf < 4; mf++) {
        #pragma unroll
        for (int nf = 0; nf < 4; nf++) {
            int col = n0 + wc * 64 + nf * 16 + r15;
            #pragma unroll
            for (int r = 0; r < 4; r++) {
                int row = m0 + wr * 64 + mf * 16 + kh * 4 + r;
                float v = acc[mf][nf][r];
                if (EPI == 0) {
                    v += bias[col];
                    outf[(size_t)row * N + col] = v;
                } else if (EPI == 1) {
                    v += bias[col];
                    outf[(size_t)row * N + col] = v / (1.f + expf(-v));
                } else if (EPI == 2) {
                    v += bias[col];
                    outf[(size_t)row * N + col] += v;
                } else {
                    outf[(size_t)row * N + col] = v;
                }
            }
        }
    }
}

// ---------------- depthwise causal conv(4) + silu, f32 in / f32 out ----------------
__global__ void conv_kernel(const float* __restrict__ h, const float* __restrict__ cw,
                            const float* __restrict__ cb, float* __restrict__ u) {
    int idx = blockIdx.x * 256 + threadIdx.x;   // over MTOT*DI
    int d = idx & (DI - 1);
    int m = idx >> 11;
    int tt = m & (LL - 1);
    float acc = cb[d];
    #pragma unroll
    for (int j = 0; j < 4; j++) {
        int tj = tt - 3 + j;
        if (tj >= 0) acc += cw[d * 4 + j] * h[(size_t)(m - 3 + j) * DI + d];
    }
    u[idx] = acc / (1.f + expf(-acc));   // silu
}

// ---------------- B/C/dt projections: one block per token row ----------------
__global__ __launch_bounds__(256) void bcd_kernel(const float* __restrict__ u,
                                                  const float* __restrict__ wB, const float* __restrict__ bB,
                                                  const float* __restrict__ wC, const float* __restrict__ bC,
                                                  const float* __restrict__ wdt, const float* __restrict__ bdt,
                                                  float* __restrict__ Bm, float* __restrict__ Cm,
                                                  float* __restrict__ dtr) {
    int m = blockIdx.x;
    int t = threadIdx.x;
    float accB[16], accC[16], accD = 0.f;
    #pragma unroll
    for (int n = 0; n < 16; n++) { accB[n] = 0.f; accC[n] = 0.f; }
    const float* ur = u + (size_t)m * DI;
    for (int k = t; k < DI; k += 256) {
        float uv = ur[k];
        #pragma unroll
        for (int n = 0; n < 16; n++) {
            accB[n] += uv * wB[n * DI + k];
            accC[n] += uv * wC[n * DI + k];
        }
        accD += uv * wdt[k];
    }
    #pragma unroll
    for (int n = 0; n < 16; n++) {
        #pragma unroll
        for (int s = 32; s; s >>= 1) {
            accB[n] += __shfl_down(accB[n], s, 64);
            accC[n] += __shfl_down(accC[n], s, 64);
        }
    }
    #pragma unroll
    for (int s = 32; s; s >>= 1) accD += __shfl_down(accD, s, 64);
    __shared__ float red[4][33];
    int lane = t & 63, w = t >> 6;
    if (lane == 0) {
        #pragma unroll
        for (int n = 0; n < 16; n++) { red[w][n] = accB[n]; red[w][16 + n] = accC[n]; }
        red[w][32] = accD;
    }
    __syncthreads();
    if (t < 33) {
        float s = red[0][t] + red[1][t] + red[2][t] + red[3][t];
        if (t < 16)       Bm[(size_t)m * 16 + t] = s + bB[t];
        else if (t < 32)  Cm[(size_t)m * 16 + (t - 16)] = s + bC[t - 16];
        else              dtr[m] = s + bdt[0];
    }
}

// ---------------- selective scan: 16-lane group per (b,d), lane = state n ----------------
// fused: softplus(dt), A=-exp(A_log), recurrence, y+Dp*u, * res, write f32
__global__ __launch_bounds__(256) void scan_kernel(const float* __restrict__ u,
                                                   const float* __restrict__ res,
                                                   const float* __restrict__ Bm, const float* __restrict__ Cm,
                                                   const float* __restrict__ dtr,
                                                   const float* __restrict__ tau,
                                                   const float* __restrict__ A_log,
                                                   const float* __restrict__ Dp,
                                                   float* __restrict__ ymul) {
    int tid = threadIdx.x;
    int g = tid >> 4, n = tid & 15;
    int blk = blockIdx.x;            // 0..255
    int b = blk >> 7;                // 128 blocks per batch
    int d = (blk & 127) * 16 + g;
    float A = -expf(A_log[d * DS + n]);
    float taud = tau[d];
    float Dpd = Dp[d];
    float h = 0.f;
    const size_t rowbase = (size_t)b * LL;
    for (int t = 0; t < LL; ++t) {
        size_t m = rowbase + t;
        float dt_ = dtr[m];
        float uu = u[m * DI + d];
        float Bn = Bm[m * 16 + n];
        float Cn = Cm[m * 16 + n];
        float xdt = taud + dt_;
        float Delta = (xdt > 20.f) ? xdt : log1pf(expf(xdt));   // softplus
        float dA = expf(Delta * A);
        h = dA * h + (Delta * uu) * Bn;
        float yp = Cn * h;
        yp += __shfl_xor(yp, 1, 64);
        yp += __shfl_xor(yp, 2, 64);
        yp += __shfl_xor(yp, 4, 64);
        yp += __shfl_xor(yp, 8, 64);
        if (n == 0) {
            ymul[m * DI + d] = (yp + Dpd * uu) * res[m * DI + d];
        }
    }
}

// ---------------- orchestration ----------------
extern "C" void kernel_launch(void* const* d_in, const int* in_sizes, int n_in,
                              void* d_out, int out_size, void* d_ws, size_t ws_size,
                              hipStream_t stream) {
    const float* emb      = (const float*)d_in[0];
    const float* norm_w   = (const float*)d_in[1];
    const float* w_in     = (const float*)d_in[2];
    const float* b_in     = (const float*)d_in[3];
    const float* w_res    = (const float*)d_in[4];
    const float* b_res    = (const float*)d_in[5];
    const float* conv_w   = (const float*)d_in[6];
    const float* conv_b   = (const float*)d_in[7];
    const float* w_B      = (const float*)d_in[8];
    const float* b_B      = (const float*)d_in[9];
    const float* w_C      = (const float*)d_in[10];
    const float* b_C      = (const float*)d_in[11];
    const float* w_dt     = (const float*)d_in[12];
    const float* b_dt     = (const float*)d_in[13];
    const float* tau_dt   = (const float*)d_in[14];
    const float* A_log    = (const float*)d_in[15];
    const float* Dp       = (const float*)d_in[16];
    const float* w_out    = (const float*)d_in[17];
    const float* b_out    = (const float*)d_in[18];
    const float* fnorm_w  = (const float*)d_in[19];
    const int*   ids      = (const int*)d_in[20];
    float* out            = (float*)d_out;

    // workspace carve-up (all f32 now, ~84 MB total)
    char* p = (char*)d_ws;
    auto alloc = [&](size_t bytes) { void* r = (void*)p; p += (bytes + 255) & ~(size_t)255; return r; };
    float* x     = (float*)alloc((size_t)MTOT * DM * 4);
    float* xn    = (float*)alloc((size_t)MTOT * DM * 4);
    float* hb    = (float*)alloc((size_t)MTOT * DI * 4);
    float* resb  = (float*)alloc((size_t)MTOT * DI * 4);
    float* ub    = (float*)alloc((size_t)MTOT * DI * 4);
    float* Bmb   = (float*)alloc((size_t)MTOT * DS * 4);
    float* Cmb   = (float*)alloc((size_t)MTOT * DS * 4);
    float* dtrb  = (float*)alloc((size_t)MTOT * 4);
    float* ymulb = (float*)alloc((size_t)MTOT * DI * 4);

    hipLaunchKernelGGL(embed_kernel, dim3(MTOT), dim3(256), 0, stream, emb, ids, x);

    for (int i = 0; i < NL; i++) {
        hipLaunchKernelGGL(rmsnorm_kernel, dim3(MTOT), dim3(256), 0, stream,
                           x, norm_w + (size_t)i * DM, xn);
        // h = xn @ w_in^T + b_in    (M=2048, N=2048, K=1024)
        hipLaunchKernelGGL((gemm_split3<0>), dim3(DI / 128, MTOT / 128), dim3(256), 0, stream,
                           xn, w_in + (size_t)i * DI * DM, b_in + (size_t)i * DI,
                           hb, MTOT, DI, DM);
        // res = silu(h @ w_res^T + b_res)   (M=2048, N=2048, K=2048)
        hipLaunchKernelGGL((gemm_split3<1>), dim3(DI / 128, MTOT / 128), dim3(256), 0, stream,
                           hb, w_res + (size_t)i * DI * DI, b_res + (size_t)i * DI,
                           resb, MTOT, DI, DI);
        // u = silu(causal_conv(h) + conv_b)
        hipLaunchKernelGGL(conv_kernel, dim3(MTOT * DI / 256), dim3(256), 0, stream,
                           hb, conv_w + (size_t)i * DI * 4, conv_b + (size_t)i * DI, ub);
        // Bm, Cm, dt_raw
        hipLaunchKernelGGL(bcd_kernel, dim3(MTOT), dim3(256), 0, stream,
                           ub, w_B + (size_t)i * DS * DI, b_B + (size_t)i * DS,
                           w_C + (size_t)i * DS * DI, b_C + (size_t)i * DS,
                           w_dt + (size_t)i * DI, b_dt + (size_t)i,
                           Bmb, Cmb, dtrb);
        // selective scan fused with (y + Dp*u) * res
        hipLaunchKernelGGL(scan_kernel, dim3(BB * DI / 16), dim3(256), 0, stream,
                           ub, resb, Bmb, Cmb, dtrb,
                           tau_dt + (size_t)i * DI, A_log + (size_t)i * DI * DS,
                           Dp + (size_t)i * DI, ymulb);
        // x += ymul @ w_out^T + b_out   (M=2048, N=1024, K=2048)
        hipLaunchKernelGGL((gemm_split3<2>), dim3(DM / 128, MTOT / 128), dim3(256), 0, stream,
                           ymulb, w_out + (size_t)i * DM * DI, b_out + (size_t)i * DM,
                           x, MTOT, DM, DI);
    }

    hipLaunchKernelGGL(rmsnorm_kernel, dim3(MTOT), dim3(256), 0, stream, x, fnorm_w, xn);
    // logits = xn @ emb^T   (M=2048, N=32000, K=1024)
    hipLaunchKernelGGL((gemm_split3<3>), dim3(NVOC / 128, MTOT / 128), dim3(256), 0, stream,
                       xn, emb, (const float*)nullptr, out, MTOT, NVOC, DM);
}